// Round 2
// baseline (63.661 us; speedup 1.0000x reference)
//
#include <hip/hip_runtime.h>

// Aspect-grouped 2-layer MLP.
//   K_A: bucket samples by aspect -> chunk metadata + permutation (1 block)
//   K_B: per (chunk of 16 same-aspect samples, 64-col h-slice): layer1 + bias
//        + relu + layer2 partials (shuffle-reduced), written to ws
//   K_C: sum 4 h-slice partials + b2 -> out (deterministic, no atomics)

constexpr int D  = 768;
constexpr int H  = 256;
constexpr int NA = 20;
constexpr int NB = 1024;
constexpr int S  = 16;            // samples per chunk
constexpr int CH_CAP = 96;        // >= NB/S + NA = 84

// ws layout (int32 indices unless noted)
constexpr int WS_TC     = 0;                  // total_chunks
constexpr int WS_AID    = 16;                 // chunk -> aspect id
constexpr int WS_BASE   = WS_AID  + CH_CAP;   // chunk -> base pos in perm
constexpr int WS_CNT    = WS_BASE + CH_CAP;   // chunk -> valid count (1..16)
constexpr int WS_PERM   = WS_CNT  + CH_CAP;   // perm[NB]
constexpr int WS_PART_F = 2048;               // FLOAT offset: part[c][hs][s][2]
constexpr size_t WS_NEEDED = (size_t)(WS_PART_F + CH_CAP * 4 * S * 2) * 4;

__global__ void bucket_kernel(const int* __restrict__ aids, int* __restrict__ wsi)
{
    __shared__ int cnt[NA];
    __shared__ int pos[NA];
    const int t = threadIdx.x;
    if (t < NA) cnt[t] = 0;
    __syncthreads();
    for (int i = t; i < NB; i += 256) atomicAdd(&cnt[aids[i]], 1);
    __syncthreads();
    if (t == 0) {
        int off = 0, tc = 0;
        for (int a = 0; a < NA; ++a) {
            pos[a] = off;
            const int n = cnt[a];
            for (int j = 0; j * S < n; ++j) {
                wsi[WS_AID  + tc] = a;
                wsi[WS_BASE + tc] = off + j * S;
                wsi[WS_CNT  + tc] = min(S, n - j * S);
                ++tc;
            }
            off += n;
        }
        wsi[WS_TC] = tc;
    }
    __syncthreads();
    for (int i = t; i < NB; i += 256) {
        const int p = atomicAdd(&pos[aids[i]], 1);
        wsi[WS_PERM + p] = i;
    }
}

__global__ __launch_bounds__(256, 2) void layer1_kernel(
    const float* __restrict__ X,
    const float* __restrict__ W1,
    const float* __restrict__ b1,
    const float* __restrict__ W2,
    const int*   __restrict__ wsi,
    float*       __restrict__ part)
{
    const int c  = blockIdx.x;
    if (c >= wsi[WS_TC]) return;
    const int hs = blockIdx.y;          // 0..3, 64-col slice

    __shared__ float xs[S][D + 4];      // +4 pad: s-groups hit distinct banks
    __shared__ int   sidx[S];

    const int t    = threadIdx.x;
    const int aid  = wsi[WS_AID  + c];
    const int base = wsi[WS_BASE + c];
    const int cntv = wsi[WS_CNT  + c];

    if (t < S) sidx[t] = wsi[WS_PERM + base + min(t, cntv - 1)];
    __syncthreads();

    // stage 16 X rows (192 float4 each)
    for (int i = t; i < S * (D / 4); i += 256) {
        const int r = i / (D / 4), c4 = i % (D / 4);
        *reinterpret_cast<float4*>(&xs[r][c4 * 4]) =
            reinterpret_cast<const float4*>(X + (size_t)sidx[r] * D)[c4];
    }
    __syncthreads();

    const int s = t >> 4;               // sample slot 0..15
    const int q = t & 15;               // col quad 0..15 within 64-col slice

    const float4* W1v = reinterpret_cast<const float4*>(
        W1 + (size_t)aid * (D * H) + hs * 64);

    float4 acc = make_float4(0.f, 0.f, 0.f, 0.f);
    #pragma unroll 4
    for (int d0 = 0; d0 < D; d0 += 4) {
        const float4 xv = *reinterpret_cast<const float4*>(&xs[s][d0]);
        const float4 w0 = W1v[(size_t)(d0 + 0) * (H / 4) + q];
        const float4 w1 = W1v[(size_t)(d0 + 1) * (H / 4) + q];
        const float4 w2 = W1v[(size_t)(d0 + 2) * (H / 4) + q];
        const float4 w3 = W1v[(size_t)(d0 + 3) * (H / 4) + q];
        acc.x = fmaf(xv.x, w0.x, acc.x); acc.y = fmaf(xv.x, w0.y, acc.y);
        acc.z = fmaf(xv.x, w0.z, acc.z); acc.w = fmaf(xv.x, w0.w, acc.w);
        acc.x = fmaf(xv.y, w1.x, acc.x); acc.y = fmaf(xv.y, w1.y, acc.y);
        acc.z = fmaf(xv.y, w1.z, acc.z); acc.w = fmaf(xv.y, w1.w, acc.w);
        acc.x = fmaf(xv.z, w2.x, acc.x); acc.y = fmaf(xv.z, w2.y, acc.y);
        acc.z = fmaf(xv.z, w2.z, acc.z); acc.w = fmaf(xv.z, w2.w, acc.w);
        acc.x = fmaf(xv.w, w3.x, acc.x); acc.y = fmaf(xv.w, w3.y, acc.y);
        acc.z = fmaf(xv.w, w3.z, acc.z); acc.w = fmaf(xv.w, w3.w, acc.w);
    }

    // bias + relu -> out1 for cols hs*64 + 4q .. +3
    const float4 bv = reinterpret_cast<const float4*>(b1 + (size_t)aid * H + hs * 64)[q];
    float4 o;
    o.x = fmaxf(acc.x + bv.x, 0.f);
    o.y = fmaxf(acc.y + bv.y, 0.f);
    o.z = fmaxf(acc.z + bv.z, 0.f);
    o.w = fmaxf(acc.w + bv.w, 0.f);

    // layer2 partial over these 4 cols; W2 (H,2) row-major -> 8 floats at col*2
    const float4* W2v = reinterpret_cast<const float4*>(
        W2 + (size_t)aid * (H * 2) + hs * 128 + q * 8);
    const float4 w2a = W2v[0];   // col 4q:   (o0,o1), col 4q+1: (o0,o1)
    const float4 w2b = W2v[1];   // col 4q+2, col 4q+3
    float p0 = o.x * w2a.x + o.y * w2a.z + o.z * w2b.x + o.w * w2b.z;
    float p1 = o.x * w2a.y + o.y * w2a.w + o.z * w2b.y + o.w * w2b.w;

    // reduce across the 16 q-lanes (contiguous within the wave)
    #pragma unroll
    for (int m = 1; m < 16; m <<= 1) {
        p0 += __shfl_xor(p0, m, 64);
        p1 += __shfl_xor(p1, m, 64);
    }
    if (q == 0) {
        float2* pp = reinterpret_cast<float2*>(part + (size_t)c * 128 + hs * 32 + s * 2);
        *pp = make_float2(p0, p1);
    }
}

__global__ void finish_kernel(const int* __restrict__ wsi,
                              const float* __restrict__ part,
                              const float* __restrict__ b2,
                              float* __restrict__ out)
{
    const int c = blockIdx.x;
    if (c >= wsi[WS_TC]) return;
    const int t = threadIdx.x;          // 64 threads, use 32
    if (t >= 32) return;
    const int s = t >> 1, o = t & 1;
    if (s >= wsi[WS_CNT + c]) return;
    const int aid  = wsi[WS_AID + c];
    const int sidx = wsi[WS_PERM + wsi[WS_BASE + c] + s];
    float v = b2[aid * 2 + o];
    #pragma unroll
    for (int hs = 0; hs < 4; ++hs)
        v += part[(size_t)c * 128 + hs * 32 + s * 2 + o];
    out[sidx * 2 + o] = v;
}

// ---------------- fallback (round-1 monolithic kernel) ----------------
__global__ __launch_bounds__(256, 4) void aspect_mlp_fallback(
    const float* __restrict__ X, const int* __restrict__ aspect_ids,
    const float* __restrict__ W1_embs, const float* __restrict__ b1_embs,
    const float* __restrict__ W2_embs, const float* __restrict__ b2_embs,
    float* __restrict__ out)
{
    __shared__ float xs[D];
    __shared__ float pl[4][H];
    __shared__ float red[4][2];
    const int b = blockIdx.x, t = threadIdx.x, w = t >> 6, l = t & 63;
    const int aid = aspect_ids[b];
    const float4* Xr = reinterpret_cast<const float4*>(X + (size_t)b * D);
    if (t < D / 4) reinterpret_cast<float4*>(xs)[t] = Xr[t];
    __syncthreads();
    const float4* W1v = reinterpret_cast<const float4*>(W1_embs + (size_t)aid * (D * H));
    float4 acc = make_float4(0.f, 0.f, 0.f, 0.f);
    const int d0 = w * (D / 4);
    for (int d = d0; d < d0 + D / 4; ++d) {
        const float xv = xs[d];
        const float4 wv = W1v[d * (H / 4) + l];
        acc.x = fmaf(xv, wv.x, acc.x); acc.y = fmaf(xv, wv.y, acc.y);
        acc.z = fmaf(xv, wv.z, acc.z); acc.w = fmaf(xv, wv.w, acc.w);
    }
    reinterpret_cast<float4*>(pl[w])[l] = acc;
    __syncthreads();
    const float o = fmaxf(pl[0][t] + pl[1][t] + pl[2][t] + pl[3][t] + b1_embs[aid * H + t], 0.f);
    const float2 w2 = reinterpret_cast<const float2*>(W2_embs)[aid * H + t];
    float p0 = o * w2.x, p1 = o * w2.y;
    for (int s = 32; s; s >>= 1) { p0 += __shfl_xor(p0, s, 64); p1 += __shfl_xor(p1, s, 64); }
    if (l == 0) { red[w][0] = p0; red[w][1] = p1; }
    __syncthreads();
    if (t == 0) {
        const float2 bias2 = reinterpret_cast<const float2*>(b2_embs)[aid];
        out[b * 2 + 0] = red[0][0] + red[1][0] + red[2][0] + red[3][0] + bias2.x;
        out[b * 2 + 1] = red[0][1] + red[1][1] + red[2][1] + red[3][1] + bias2.y;
    }
}

extern "C" void kernel_launch(void* const* d_in, const int* in_sizes, int n_in,
                              void* d_out, int out_size, void* d_ws, size_t ws_size,
                              hipStream_t stream) {
    const float* X          = (const float*)d_in[0];
    const int*   aspect_ids = (const int*)d_in[1];
    const float* W1_embs    = (const float*)d_in[2];
    const float* b1_embs    = (const float*)d_in[3];
    const float* W2_embs    = (const float*)d_in[4];
    const float* b2_embs    = (const float*)d_in[5];
    float*       out        = (float*)d_out;

    const int Brt = in_sizes[0] / D;
    const int na  = in_sizes[2] / (D * H);

    if (Brt != NB || na != NA || ws_size < WS_NEEDED) {
        aspect_mlp_fallback<<<Brt, 256, 0, stream>>>(
            X, aspect_ids, W1_embs, b1_embs, W2_embs, b2_embs, out);
        return;
    }

    int*   wsi  = (int*)d_ws;
    float* part = (float*)d_ws + WS_PART_F;

    bucket_kernel<<<1, 256, 0, stream>>>(aspect_ids, wsi);
    layer1_kernel<<<dim3(CH_CAP, 4), 256, 0, stream>>>(
        X, W1_embs, b1_embs, W2_embs, wsi, part);
    finish_kernel<<<CH_CAP, 64, 0, stream>>>(wsi, part, b2_embs, out);
}

// Round 3
// 28.742 us; speedup vs baseline: 2.2149x; 2.2149x over previous
//
#include <hip/hip_runtime.h>

// Aspect-grouped 2-layer MLP, register-blocked.
//   bucket:  sample -> aspect buckets, chunk meta, permutation (1 block)
//   layer1:  per (chunk of 16 same-aspect samples, 64-col h-slice):
//            512 thr / 8 waves; wave w covers d in [w*96, w*96+96);
//            thread owns 4 samples x 4 cols -> 16 FMA per W1 float4 load;
//            LDS reduce over waves, bias+relu+W2 partial, 16-lane shuffle,
//            write part[hs][sample] (float2)
//   finish:  out[s][o] = b2 + sum_hs part[hs][s][o]   (by original sample id)

constexpr int D  = 768;
constexpr int H  = 256;
constexpr int NA = 20;
constexpr int NB = 1024;
constexpr int S  = 16;            // samples per chunk
constexpr int CH_CAP = 96;        // >= NB/S + NA = 84
constexpr int DP = D + 4;         // padded LDS row

// ws layout: int region then float region
constexpr int WS_TC   = 0;
constexpr int WS_AID  = 16;
constexpr int WS_BASE = WS_AID  + CH_CAP;
constexpr int WS_CNT  = WS_BASE + CH_CAP;
constexpr int WS_PERM = WS_CNT  + CH_CAP;     // + NB
constexpr int WS_PART_F = 2048;               // float2 part[4][NB]
constexpr size_t WS_NEEDED = (size_t)(WS_PART_F + 4 * NB * 2) * 4;

__global__ void bucket_kernel(const int* __restrict__ aids, int* __restrict__ wsi)
{
    __shared__ int cnt[NA], off[NA], cbase[NA], pos[NA];
    const int t = threadIdx.x;
    if (t < NA) cnt[t] = 0;
    __syncthreads();
    for (int i = t; i < NB; i += 256) atomicAdd(&cnt[aids[i]], 1);
    __syncthreads();
    if (t == 0) {
        int o = 0, cb = 0;
        for (int a = 0; a < NA; ++a) {
            off[a] = o; cbase[a] = cb;
            o  += cnt[a];
            cb += (cnt[a] + S - 1) / S;
        }
        wsi[WS_TC] = cb;
    }
    __syncthreads();
    if (t < NA) {
        pos[t] = off[t];
        const int n = cnt[t], cb = cbase[t];
        for (int j = 0; j * S < n; ++j) {
            wsi[WS_AID  + cb + j] = t;
            wsi[WS_BASE + cb + j] = off[t] + j * S;
            wsi[WS_CNT  + cb + j] = min(S, n - j * S);
        }
    }
    __syncthreads();
    for (int i = t; i < NB; i += 256) {
        const int p = atomicAdd(&pos[aids[i]], 1);
        wsi[WS_PERM + p] = i;
    }
}

__global__ __launch_bounds__(512, 2) void layer1_kernel(
    const float* __restrict__ X,
    const float* __restrict__ W1,
    const float* __restrict__ b1,
    const float* __restrict__ W2,
    const int*   __restrict__ wsi,
    float*       __restrict__ part)   // float2 [4][NB]
{
    const int c = blockIdx.x;
    if (c >= wsi[WS_TC]) return;
    const int hs = blockIdx.y;                 // 64-col slice

    __shared__ __align__(16) float smem[S * DP];   // xs, later overlaid by red
    __shared__ int sidx[S];

    const int t    = threadIdx.x;
    const int aid  = wsi[WS_AID  + c];
    const int base = wsi[WS_BASE + c];
    const int cntv = wsi[WS_CNT  + c];

    if (t < S) sidx[t] = wsi[WS_PERM + base + min(t, cntv - 1)];
    __syncthreads();

    // stage 16 X rows (192 float4 each), coalesced
    for (int i = t; i < S * (D / 4); i += 512) {
        const int r = i / (D / 4), c4 = i - r * (D / 4);
        *reinterpret_cast<float4*>(&smem[r * DP + c4 * 4]) =
            reinterpret_cast<const float4*>(X + (size_t)sidx[r] * D)[c4];
    }
    __syncthreads();

    const int w  = t >> 6;        // wave 0..7 -> d-slice
    const int l  = t & 63;
    const int sq = l >> 4;        // sample quad 0..3
    const int cq = l & 15;        // col quad within 64-col slice

    const float4* W1v = reinterpret_cast<const float4*>(
        W1 + (size_t)aid * (D * H)) + hs * 16;   // + col offset (float4 units)

    const int d0 = w * (D / 8);                  // 96 rows per wave
    const float* xp = &smem[(sq * 4) * DP + d0];

    float4 a0 = {0,0,0,0}, a1 = {0,0,0,0}, a2 = {0,0,0,0}, a3 = {0,0,0,0};
    #pragma unroll 4
    for (int d = 0; d < D / 8; ++d) {
        const float4 wv = W1v[(size_t)(d0 + d) * (H / 4) + cq];
        const float x0 = xp[d];
        const float x1 = xp[DP + d];
        const float x2 = xp[2 * DP + d];
        const float x3 = xp[3 * DP + d];
        a0.x = fmaf(x0, wv.x, a0.x); a0.y = fmaf(x0, wv.y, a0.y);
        a0.z = fmaf(x0, wv.z, a0.z); a0.w = fmaf(x0, wv.w, a0.w);
        a1.x = fmaf(x1, wv.x, a1.x); a1.y = fmaf(x1, wv.y, a1.y);
        a1.z = fmaf(x1, wv.z, a1.z); a1.w = fmaf(x1, wv.w, a1.w);
        a2.x = fmaf(x2, wv.x, a2.x); a2.y = fmaf(x2, wv.y, a2.y);
        a2.z = fmaf(x2, wv.z, a2.z); a2.w = fmaf(x2, wv.w, a2.w);
        a3.x = fmaf(x3, wv.x, a3.x); a3.y = fmaf(x3, wv.y, a3.y);
        a3.z = fmaf(x3, wv.z, a3.z); a3.w = fmaf(x3, wv.w, a3.w);
    }
    __syncthreads();                       // everyone done reading xs

    // overlay: red[w][s][cq] float4 = 8*16*16*16B = 32 KB
    float4* red = reinterpret_cast<float4*>(smem);
    red[(w * S + sq * 4 + 0) * 16 + cq] = a0;
    red[(w * S + sq * 4 + 1) * 16 + cq] = a1;
    red[(w * S + sq * 4 + 2) * 16 + cq] = a2;
    red[(w * S + sq * 4 + 3) * 16 + cq] = a3;
    __syncthreads();

    if (t < 256) {
        const int s = t >> 4, q = t & 15;
        float4 v = red[(0 * S + s) * 16 + q];
        #pragma unroll
        for (int ww = 1; ww < 8; ++ww) {
            const float4 r = red[(ww * S + s) * 16 + q];
            v.x += r.x; v.y += r.y; v.z += r.z; v.w += r.w;
        }
        const float4 bv = reinterpret_cast<const float4*>(
            b1 + (size_t)aid * H + hs * 64)[q];
        float4 o;
        o.x = fmaxf(v.x + bv.x, 0.f);
        o.y = fmaxf(v.y + bv.y, 0.f);
        o.z = fmaxf(v.z + bv.z, 0.f);
        o.w = fmaxf(v.w + bv.w, 0.f);

        const float4* W2v = reinterpret_cast<const float4*>(
            W2 + (size_t)aid * (H * 2) + hs * 128 + q * 8);
        const float4 w2a = W2v[0];
        const float4 w2b = W2v[1];
        float p0 = o.x * w2a.x + o.y * w2a.z + o.z * w2b.x + o.w * w2b.z;
        float p1 = o.x * w2a.y + o.y * w2a.w + o.z * w2b.y + o.w * w2b.w;
        #pragma unroll
        for (int m = 1; m < 16; m <<= 1) {
            p0 += __shfl_xor(p0, m, 64);
            p1 += __shfl_xor(p1, m, 64);
        }
        if (q == 0) {
            reinterpret_cast<float2*>(part)[hs * NB + sidx[s]] =
                make_float2(p0, p1);
        }
    }
}

__global__ void finish_kernel(const int* __restrict__ aids,
                              const float* __restrict__ part,
                              const float* __restrict__ b2,
                              float* __restrict__ out)
{
    const int i = blockIdx.x * 512 + threadIdx.x;
    if (i >= NB * 2) return;
    const int s = i >> 1, o = i & 1;
    float v = b2[aids[s] * 2 + o];
    #pragma unroll
    for (int hs = 0; hs < 4; ++hs)
        v += part[(hs * NB + s) * 2 + o];
    out[i] = v;
}

// ---------------- fallback (round-1 monolithic kernel) ----------------
__global__ __launch_bounds__(256, 4) void aspect_mlp_fallback(
    const float* __restrict__ X, const int* __restrict__ aspect_ids,
    const float* __restrict__ W1_embs, const float* __restrict__ b1_embs,
    const float* __restrict__ W2_embs, const float* __restrict__ b2_embs,
    float* __restrict__ out)
{
    __shared__ float xs[D];
    __shared__ float pl[4][H];
    __shared__ float red[4][2];
    const int b = blockIdx.x, t = threadIdx.x, w = t >> 6, l = t & 63;
    const int aid = aspect_ids[b];
    const float4* Xr = reinterpret_cast<const float4*>(X + (size_t)b * D);
    if (t < D / 4) reinterpret_cast<float4*>(xs)[t] = Xr[t];
    __syncthreads();
    const float4* W1v = reinterpret_cast<const float4*>(W1_embs + (size_t)aid * (D * H));
    float4 acc = make_float4(0.f, 0.f, 0.f, 0.f);
    const int d0 = w * (D / 4);
    for (int d = d0; d < d0 + D / 4; ++d) {
        const float xv = xs[d];
        const float4 wv = W1v[d * (H / 4) + l];
        acc.x = fmaf(xv, wv.x, acc.x); acc.y = fmaf(xv, wv.y, acc.y);
        acc.z = fmaf(xv, wv.z, acc.z); acc.w = fmaf(xv, wv.w, acc.w);
    }
    reinterpret_cast<float4*>(pl[w])[l] = acc;
    __syncthreads();
    const float o = fmaxf(pl[0][t] + pl[1][t] + pl[2][t] + pl[3][t] + b1_embs[aid * H + t], 0.f);
    const float2 w2 = reinterpret_cast<const float2*>(W2_embs)[aid * H + t];
    float p0 = o * w2.x, p1 = o * w2.y;
    for (int s = 32; s; s >>= 1) { p0 += __shfl_xor(p0, s, 64); p1 += __shfl_xor(p1, s, 64); }
    if (l == 0) { red[w][0] = p0; red[w][1] = p1; }
    __syncthreads();
    if (t == 0) {
        const float2 bias2 = reinterpret_cast<const float2*>(b2_embs)[aid];
        out[b * 2 + 0] = red[0][0] + red[1][0] + red[2][0] + red[3][0] + bias2.x;
        out[b * 2 + 1] = red[0][1] + red[1][1] + red[2][1] + red[3][1] + bias2.y;
    }
}

extern "C" void kernel_launch(void* const* d_in, const int* in_sizes, int n_in,
                              void* d_out, int out_size, void* d_ws, size_t ws_size,
                              hipStream_t stream) {
    const float* X          = (const float*)d_in[0];
    const int*   aspect_ids = (const int*)d_in[1];
    const float* W1_embs    = (const float*)d_in[2];
    const float* b1_embs    = (const float*)d_in[3];
    const float* W2_embs    = (const float*)d_in[4];
    const float* b2_embs    = (const float*)d_in[5];
    float*       out        = (float*)d_out;

    const int Brt = in_sizes[0] / D;
    const int na  = in_sizes[2] / (D * H);

    if (Brt != NB || na != NA || ws_size < WS_NEEDED) {
        aspect_mlp_fallback<<<Brt, 256, 0, stream>>>(
            X, aspect_ids, W1_embs, b1_embs, W2_embs, b2_embs, out);
        return;
    }

    int*   wsi  = (int*)d_ws;
    float* part = (float*)d_ws + WS_PART_F;

    bucket_kernel<<<1, 256, 0, stream>>>(aspect_ids, wsi);
    layer1_kernel<<<dim3(CH_CAP, 4), 512, 0, stream>>>(
        X, W1_embs, b1_embs, W2_embs, wsi, part);
    finish_kernel<<<4, 512, 0, stream>>>(aspect_ids, part, b2_embs, out);
}